// Round 16
// baseline (118.961 us; speedup 1.0000x reference)
//
#include <hip/hip_runtime.h>
#include <hip/hip_bf16.h>

// Non-backtracking random walk, 32 steps.
// out = [walks (steps+1,n) ; walk_edges (steps,n)] int32.
//
// R15 (resubmit; code unchanged — round 15 was a broker failure, same
// pattern as R8->R10): drop the packing entirely. A raw adj_nodes row is
// EXACTLY one 64B line (16 x int32, aligned), so the walker gathers
// directly: ONE unconditional lane-load per step; the predicated alt
// (P=1/16) hits the SAME line (L1). Strictly fewer L2 requests than the
// packed path (entry + hbits from a straddling 36B row), and the pack
// kernel (~4us) + its memset vanish from every iteration. Keep R8/R10-
// proven config: 2 chains/thread, all-32 choices preload, interleaved nt
// stores (R14 showed batching hurts). Tiny check kernel still verifies
// deg==16 / offset==16v; fallback on violation.

#define DEG 16
#define CHAINS 2

__global__ void check_kernel(const int* __restrict__ degrees,
                             const int* __restrict__ adj_offset,
                             int n, int* __restrict__ flag) {
    int v = blockIdx.x * blockDim.x + threadIdx.x;
    if (v < n) {
        if (degrees[v] != DEG || adj_offset[v] != v * DEG)
            atomicOr(flag, 1);   // executes only on violation
    }
}

template <int STEPS>
__global__ __launch_bounds__(64) void walker_fast2(
    const int* __restrict__ adj_nodes,
    const int* __restrict__ adj_offset,
    const int* __restrict__ degrees,
    const int* __restrict__ choices,
    int* __restrict__ out, int n, int h,
    const int* __restrict__ flag) {

    int t = blockIdx.x * blockDim.x + threadIdx.x;
    if (t >= h) return;

    int* walks      = out;                    // [STEPS+1, n]
    int* walk_edges = out + (STEPS + 1) * n;  // [STEPS, n]

    int w0 = t;
    int w1 = t + h;
    bool has1 = (w1 < n);
    int w1s = has1 ? w1 : w0;

    __builtin_nontemporal_store(w0, &walks[w0]);
    if (has1) __builtin_nontemporal_store(w1, &walks[w1]);

    if (*flag == 0) {
        // ---- fast path: uniform CSR deg=16, raw 64B rows, 2 chains ----
        int c0[STEPS], c1[STEPS];
#pragma unroll
        for (int i = 0; i < STEPS; ++i) {
            c0[i] = __builtin_nontemporal_load(&choices[i * n + w0]);
            c1[i] = __builtin_nontemporal_load(&choices[i * n + w1s]);
        }

        int prev0 = -1, cur0 = w0;
        int prev1 = -1, cur1 = w1s;
#pragma unroll
        for (int i = 0; i < STEPS; ++i) {
            unsigned ch0 = (unsigned)c0[i];
            unsigned ch1 = (unsigned)c1[i];
            unsigned e0 = ch0 & (DEG - 1);
            unsigned e1 = ch1 & (DEG - 1);
            int base0 = cur0 << 4;            // row = one 64B line
            int base1 = cur1 << 4;

            // two unconditional gathers (one per chain), issued together
            int n00 = adj_nodes[base0 + (int)e0];
            int n10 = adj_nodes[base1 + (int)e1];

            int nw0 = n00, nw1 = n10;
            unsigned ef0 = e0, ef1 = e1;
            // predicated alt: same 64B line -> L1 hit for the few bt lanes
            if (n00 == prev0) {
                unsigned a0 = (e0 + 1u + ch0 % (DEG - 1)) & (DEG - 1);
                nw0 = adj_nodes[base0 + (int)a0];
                ef0 = a0;
            }
            if (n10 == prev1) {
                unsigned a1 = (e1 + 1u + ch1 % (DEG - 1)) & (DEG - 1);
                nw1 = adj_nodes[base1 + (int)a1];
                ef1 = a1;
            }

            __builtin_nontemporal_store(nw0, &walks[(i + 1) * n + w0]);
            __builtin_nontemporal_store(base0 + (int)ef0, &walk_edges[i * n + w0]);
            if (has1) {
                __builtin_nontemporal_store(nw1, &walks[(i + 1) * n + w1]);
                __builtin_nontemporal_store(base1 + (int)ef1, &walk_edges[i * n + w1]);
            }
            prev0 = cur0; cur0 = nw0;
            prev1 = cur1; cur1 = nw1;
        }
    } else {
        // ---- general fallback: 2 dependent gathers/step ----
        for (int k = 0; k < 2; ++k) {
            int w = (k == 0) ? w0 : w1;
            if (w >= n) break;
            int prev = -1, cur = w;
            for (int i = 0; i < STEPS; ++i) {
                int chv = choices[i * n + w];
                int deg = degrees[cur];
                int off = adj_offset[cur];
                int nb  = deg - 1 > 1 ? deg - 1 : 1;

                int e      = chv % deg;
                int chosen = off + e;
                int alt    = off + (e + 1 + chv % nb) % deg;

                int nv0 = adj_nodes[chosen];
                int nv1 = adj_nodes[alt];

                bool bt = (nv0 == prev);
                int nw  = bt ? nv1 : nv0;
                walks[(i + 1) * n + w] = nw;
                walk_edges[i * n + w]  = bt ? alt : chosen;
                prev = cur;
                cur  = nw;
            }
        }
    }
}

__global__ __launch_bounds__(256) void walker_generic(
    const int* __restrict__ adj_nodes,
    const int* __restrict__ adj_offset,
    const int* __restrict__ degrees,
    const int* __restrict__ choices,
    int* __restrict__ out, int n, int steps) {

    int w = blockIdx.x * blockDim.x + threadIdx.x;
    if (w >= n) return;

    int* walks      = out;
    int* walk_edges = out + (steps + 1) * n;
    walks[w] = w;

    int prev = -1, cur = w;
    for (int i = 0; i < steps; ++i) {
        int chv = choices[i * n + w];
        int deg = degrees[cur];
        int off = adj_offset[cur];
        int nb  = deg - 1 > 1 ? deg - 1 : 1;

        int e      = chv % deg;
        int chosen = off + e;
        int alt    = off + (e + 1 + chv % nb) % deg;

        int nv0 = adj_nodes[chosen];
        int nv1 = adj_nodes[alt];

        bool bt = (nv0 == prev);
        int nw  = bt ? nv1 : nv0;
        walks[(i + 1) * n + w] = nw;
        walk_edges[i * n + w]  = bt ? alt : chosen;
        prev = cur;
        cur  = nw;
    }
}

extern "C" void kernel_launch(void* const* d_in, const int* in_sizes, int n_in,
                              void* d_out, int out_size, void* d_ws, size_t ws_size,
                              hipStream_t stream) {
    // inputs: 0=x (unused), 1=adj_nodes, 2=adj_offset, 3=degrees, 4=choices
    const int* adj_nodes  = (const int*)d_in[1];
    const int* adj_offset = (const int*)d_in[2];
    const int* degrees    = (const int*)d_in[3];
    const int* choices    = (const int*)d_in[4];
    int* out = (int*)d_out;

    int n     = in_sizes[2];
    int steps = in_sizes[4] / n;

    if (steps == 32 && ws_size >= 4) {
        int* flag = (int*)d_ws;
        hipMemsetAsync(flag, 0, sizeof(int), stream);
        int pb = 256, pg = (n + pb - 1) / pb;
        check_kernel<<<pg, pb, 0, stream>>>(degrees, adj_offset, n, flag);
        int h  = (n + CHAINS - 1) / CHAINS;
        int wb = 64, wg = (h + wb - 1) / wb;
        walker_fast2<32><<<wg, wb, 0, stream>>>(adj_nodes, adj_offset, degrees,
                                                choices, out, n, h, flag);
    } else {
        int block = 256, grid = (n + block - 1) / block;
        walker_generic<<<grid, block, 0, stream>>>(adj_nodes, adj_offset,
                                                   degrees, choices, out, n, steps);
    }
}

// Round 17
// 110.738 us; speedup vs baseline: 1.0743x; 1.0743x over previous
//
#include <hip/hip_runtime.h>
#include <hip/hip_bf16.h>

// Non-backtracking random walk, 32 steps.
// out = [walks (steps+1,n) ; walk_edges (steps,n)] int32.
//
// R17: take the output stores out of the gather chain via LDS staging.
// ds_write increments lgkmcnt (NOT vmcnt), so during the 32-step loop the
// vm FIFO holds only gathers -> a gather's s_waitcnt no longer drains the
// 4 older HBM store-acks per step (~600-900cyc each). After the loop, a
// flush reads LDS and issues all global nt stores. Unlike R14's register
// batching (regressed: +64 VGPRs, stores still in FIFO), this costs zero
// registers and zero vm-queue slots. LDS 32KB/block, [step][tid] layout ->
// 2-way bank alias only (free). Base = R8/R10 best (106.3us): stride-18
// u16 rows w/ in-row hbits (3.6MB, L2-fitting — R15 proved raw 6.4MB rows
// cost +17us), 2 chains/thread, predicated alt gather, nt streaming.
// Pack kernel verifies uniform CSR (deg==16, offset==16v, ids<2^17); on
// violation walker takes a fully-general fallback.

#define DEG 16
#define CHAINS 2

__global__ void pack_check_kernel(const int* __restrict__ adj_nodes,
                                  const int* __restrict__ adj_offset,
                                  const int* __restrict__ degrees,
                                  int n,
                                  unsigned int* __restrict__ pk32,  // 9 u32 per row (36B)
                                  int* __restrict__ flag) {
    int v = blockIdx.x * blockDim.x + threadIdx.x;
    if (v >= n) return;

    bool bad = (degrees[v] != DEG) || (adj_offset[v] != v * DEG);

    const uint4* row4 = (const uint4*)(adj_nodes + (size_t)v * DEG); // 64B-aligned
    uint4 r[4];
    r[0] = row4[0]; r[1] = row4[1]; r[2] = row4[2]; r[3] = row4[3];
    const unsigned* rr = (const unsigned*)r;

    unsigned wv[8];
    unsigned hbits = 0;
#pragma unroll
    for (int j = 0; j < 8; ++j) {
        unsigned u0 = rr[2 * j];
        unsigned u1 = rr[2 * j + 1];
        if (u0 >= 131072u || u1 >= 131072u) bad = true;   // needs >17 bits
        wv[j] = (u0 & 0xffffu) | ((u1 & 0xffffu) << 16);
        hbits |= ((u0 >> 16) & 1u) << (2 * j);
        hbits |= ((u1 >> 16) & 1u) << (2 * j + 1);
    }
    unsigned int* dst = pk32 + (size_t)v * 9;   // 36B/row, 4B-aligned
#pragma unroll
    for (int j = 0; j < 8; ++j) dst[j] = wv[j];
    dst[8] = hbits;                              // u16 hbits at r[16]

    if (bad) atomicOr(flag, 1);
}

template <int STEPS>
__global__ __launch_bounds__(64) void walker_fast2(
    const unsigned short* __restrict__ pk,   // stride-18 u16 rows
    const int* __restrict__ choices,
    int* __restrict__ out, int n, int h,
    const int* __restrict__ flag,
    const int* __restrict__ adj_nodes,
    const int* __restrict__ adj_offset,
    const int* __restrict__ degrees) {

    // LDS staging: outputs leave the vm FIFO during the step loop.
    __shared__ int s_on0[STEPS][64];
    __shared__ int s_oe0[STEPS][64];
    __shared__ int s_on1[STEPS][64];
    __shared__ int s_oe1[STEPS][64];

    int t = blockIdx.x * blockDim.x + threadIdx.x;
    if (t >= h) return;
    int tid = threadIdx.x;

    int* walks      = out;                    // [STEPS+1, n]
    int* walk_edges = out + (STEPS + 1) * n;  // [STEPS, n]

    int w0 = t;
    int w1 = t + h;
    bool has1 = (w1 < n);
    int w1s = has1 ? w1 : w0;

    __builtin_nontemporal_store(w0, &walks[w0]);
    if (has1) __builtin_nontemporal_store(w1, &walks[w1]);

    if (*flag == 0) {
        // ---- fast path: 2 chains, predicated alt, store-free step chain ----
        int c0[STEPS], c1[STEPS];
#pragma unroll
        for (int i = 0; i < STEPS; ++i) {
            c0[i] = __builtin_nontemporal_load(&choices[i * n + w0]);
            c1[i] = __builtin_nontemporal_load(&choices[i * n + w1s]);
        }

        int prev0 = -1, cur0 = w0;
        int prev1 = -1, cur1 = w1s;
#pragma unroll
        for (int i = 0; i < STEPS; ++i) {
            unsigned ch0 = (unsigned)c0[i];
            unsigned ch1 = (unsigned)c1[i];
            unsigned e0 = ch0 & (DEG - 1);
            unsigned e1 = ch1 & (DEG - 1);

            const unsigned short* r0 = pk + (unsigned)cur0 * 18u;
            const unsigned short* r1 = pk + (unsigned)cur1 * 18u;

            // four unconditional gathers, issued together (only vm ops in FIFO)
            unsigned l00 = r0[e0];
            unsigned hb0 = r0[16];
            unsigned l10 = r1[e1];
            unsigned hb1 = r1[16];

            int n00 = (int)(l00 | (((hb0 >> e0) & 1u) << 16));
            int n10 = (int)(l10 | (((hb1 >> e1) & 1u) << 16));

            int nw0 = n00, nw1 = n10;
            unsigned ef0 = e0, ef1 = e1;
            // predicated alt gathers: ~1/16 of lanes
            if (n00 == prev0) {
                unsigned a0 = (e0 + 1u + ch0 % (DEG - 1)) & (DEG - 1);
                unsigned l01 = r0[a0];
                nw0 = (int)(l01 | (((hb0 >> a0) & 1u) << 16));
                ef0 = a0;
            }
            if (n10 == prev1) {
                unsigned a1 = (e1 + 1u + ch1 % (DEG - 1)) & (DEG - 1);
                unsigned l11 = r1[a1];
                nw1 = (int)(l11 | (((hb1 >> a1) & 1u) << 16));
                ef1 = a1;
            }

            // outputs -> LDS (lgkmcnt, fire-and-forget; no vmcnt pollution)
            s_on0[i][tid] = nw0;
            s_oe0[i][tid] = (cur0 << 4) + (int)ef0;
            s_on1[i][tid] = nw1;
            s_oe1[i][tid] = (cur1 << 4) + (int)ef1;

            prev0 = cur0; cur0 = nw0;
            prev1 = cur1; cur1 = nw1;
        }

        // flush: read own LDS column, issue all global nt stores
#pragma unroll
        for (int i = 0; i < STEPS; ++i) {
            __builtin_nontemporal_store(s_on0[i][tid], &walks[(i + 1) * n + w0]);
            __builtin_nontemporal_store(s_oe0[i][tid], &walk_edges[i * n + w0]);
            if (has1) {
                __builtin_nontemporal_store(s_on1[i][tid], &walks[(i + 1) * n + w1]);
                __builtin_nontemporal_store(s_oe1[i][tid], &walk_edges[i * n + w1]);
            }
        }
    } else {
        // ---- general fallback: 2 dependent gathers/step ----
        for (int k = 0; k < 2; ++k) {
            int w = (k == 0) ? w0 : w1;
            if (w >= n) break;
            int prev = -1, cur = w;
            for (int i = 0; i < STEPS; ++i) {
                int chv = choices[i * n + w];
                int deg = degrees[cur];
                int off = adj_offset[cur];
                int nb  = deg - 1 > 1 ? deg - 1 : 1;

                int e      = chv % deg;
                int chosen = off + e;
                int alt    = off + (e + 1 + chv % nb) % deg;

                int nv0 = adj_nodes[chosen];
                int nv1 = adj_nodes[alt];

                bool bt = (nv0 == prev);
                int nw  = bt ? nv1 : nv0;
                walks[(i + 1) * n + w] = nw;
                walk_edges[i * n + w]  = bt ? alt : chosen;
                prev = cur;
                cur  = nw;
            }
        }
    }
}

__global__ __launch_bounds__(256) void walker_generic(
    const int* __restrict__ adj_nodes,
    const int* __restrict__ adj_offset,
    const int* __restrict__ degrees,
    const int* __restrict__ choices,
    int* __restrict__ out, int n, int steps) {

    int w = blockIdx.x * blockDim.x + threadIdx.x;
    if (w >= n) return;

    int* walks      = out;
    int* walk_edges = out + (steps + 1) * n;
    walks[w] = w;

    int prev = -1, cur = w;
    for (int i = 0; i < steps; ++i) {
        int chv = choices[i * n + w];
        int deg = degrees[cur];
        int off = adj_offset[cur];
        int nb  = deg - 1 > 1 ? deg - 1 : 1;

        int e      = chv % deg;
        int chosen = off + e;
        int alt    = off + (e + 1 + chv % nb) % deg;

        int nv0 = adj_nodes[chosen];
        int nv1 = adj_nodes[alt];

        bool bt = (nv0 == prev);
        int nw  = bt ? nv1 : nv0;
        walks[(i + 1) * n + w] = nw;
        walk_edges[i * n + w]  = bt ? alt : chosen;
        prev = cur;
        cur  = nw;
    }
}

extern "C" void kernel_launch(void* const* d_in, const int* in_sizes, int n_in,
                              void* d_out, int out_size, void* d_ws, size_t ws_size,
                              hipStream_t stream) {
    // inputs: 0=x (unused), 1=adj_nodes, 2=adj_offset, 3=degrees, 4=choices
    const int* adj_nodes  = (const int*)d_in[1];
    const int* adj_offset = (const int*)d_in[2];
    const int* degrees    = (const int*)d_in[3];
    const int* choices    = (const int*)d_in[4];
    int* out = (int*)d_out;

    int n     = in_sizes[2];
    int steps = in_sizes[4] / n;

    // ws layout: [0,4) flag | [64, 64+36n) packed stride-18 rows
    size_t pk_off = 64;
    size_t need   = pk_off + (size_t)n * 36;

    if (steps == 32 && ws_size >= need) {
        int* flag = (int*)d_ws;
        unsigned int*   pk32 = (unsigned int*)((char*)d_ws + pk_off);
        unsigned short* pk   = (unsigned short*)pk32;

        hipMemsetAsync(flag, 0, sizeof(int), stream);
        int pb = 256, pg = (n + pb - 1) / pb;
        pack_check_kernel<<<pg, pb, 0, stream>>>(adj_nodes, adj_offset, degrees,
                                                 n, pk32, flag);
        int h  = (n + CHAINS - 1) / CHAINS;
        int wb = 64, wg = (h + wb - 1) / wb;
        walker_fast2<32><<<wg, wb, 0, stream>>>(pk, choices, out, n, h, flag,
                                                adj_nodes, adj_offset, degrees);
    } else {
        int block = 256, grid = (n + block - 1) / block;
        walker_generic<<<grid, block, 0, stream>>>(adj_nodes, adj_offset,
                                                   degrees, choices, out, n, steps);
    }
}